// Round 1
// baseline (179.325 us; speedup 1.0000x reference)
//
#include <hip/hip_runtime.h>
#include <stdint.h>

typedef unsigned short u16;
typedef unsigned int   u32;
typedef __attribute__((ext_vector_type(8))) short short8;
typedef __attribute__((ext_vector_type(4))) float f32x4;

#define DEV static __device__ __forceinline__

static constexpr int Bc = 2, Tc = 2048, Hc = 768, NH = 12, HD = 64;
static constexpr int BTc = Bc * Tc;      // 4096 rows
static constexpr int N3 = 3 * Hc;        // 2304
static constexpr float QSCALE = 0.125f * 1.44269504088896f; // 1/sqrt(64) * log2(e)

DEV u16 f2bf(float f) {
  u32 u = __float_as_uint(f);
  u32 r = (u + 0x7fffu + ((u >> 16) & 1u)) >> 16;  // RNE
  return (u16)r;
}

DEV float fexp2(float x) {
#if __has_builtin(__builtin_amdgcn_exp2f)
  return __builtin_amdgcn_exp2f(x);
#else
  return exp2f(x);
#endif
}

DEV void gl_lds16(const u16* g, u16* l) {
  __builtin_amdgcn_global_load_lds(
      (const __attribute__((address_space(1))) u32*)g,
      (__attribute__((address_space(3))) u32*)l, 16, 0, 0);
}

#define MFMA(a, b, c) __builtin_amdgcn_mfma_f32_16x16x32_bf16((a), (b), (c), 0, 0, 0)

// ---------------- cast x (fp32 -> bf16), 8 elems/thread ----------------
__global__ void k_cvt(const float4* __restrict__ in, uint4* __restrict__ out, int n8) {
  int i = blockIdx.x * 256 + threadIdx.x;
  if (i >= n8) return;
  float4 a = in[2 * i], b = in[2 * i + 1];
  uint4 o;
  o.x = f2bf(a.x) | ((u32)f2bf(a.y) << 16);
  o.y = f2bf(a.z) | ((u32)f2bf(a.w) << 16);
  o.z = f2bf(b.x) | ((u32)f2bf(b.y) << 16);
  o.w = f2bf(b.z) | ((u32)f2bf(b.w) << 16);
  out[i] = o;
}

// ------------- transpose + cast weights: in fp32 [R][C] -> out bf16 [C][R] -------------
__global__ __launch_bounds__(256) void k_transpose_w(const float* __restrict__ in,
                                                     u16* __restrict__ out, int R, int C) {
  __shared__ u16 tile[64][65];
  int c0 = blockIdx.x * 64, r0 = blockIdx.y * 64;
  int tx = threadIdx.x, ty = threadIdx.y;  // block (64,4)
  for (int i = ty; i < 64; i += 4)
    tile[i][tx] = f2bf(in[(size_t)(r0 + i) * C + c0 + tx]);
  __syncthreads();
  for (int i = ty; i < 64; i += 4)
    out[(size_t)(c0 + i) * R + r0 + tx] = tile[tx][i];
}

// ------------- transpose V per head: [bh][2048][64] -> VT [bh][64][2048] (bf16) -------------
__global__ __launch_bounds__(256) void k_transpose_v(const u16* __restrict__ V,
                                                     u16* __restrict__ VT) {
  __shared__ u16 tile[64][65];
  int bh = blockIdx.y;
  int t0 = blockIdx.x * 64;
  const u16* src = V + (size_t)bh * Tc * HD;
  u16* dst = VT + (size_t)bh * Tc * HD;
  int tx = threadIdx.x, ty = threadIdx.y;
  for (int i = ty; i < 64; i += 4)
    tile[i][tx] = src[(size_t)(t0 + i) * HD + tx];
  __syncthreads();
  for (int i = ty; i < 64; i += 4)
    dst[(size_t)i * Tc + t0 + tx] = tile[tx][i];
}

// ---------------- GEMM: C = A[M,K] * BT[N,K]^T (+bias), bf16 in, fp32 acc ----------------
// EPI=0: scatter into Qh(scaled)/Kh/Vh per-head bf16 layouts. EPI=1: fp32 out + bias.
template <int EPI>
__global__ __launch_bounds__(256) void k_gemm(const u16* __restrict__ A,
                                              const u16* __restrict__ BTm,
                                              const float* __restrict__ bias,
                                              u16* __restrict__ oQ, u16* __restrict__ oK,
                                              u16* __restrict__ oV, float* __restrict__ oF,
                                              int M, int N, int K) {
  __shared__ u16 As[128 * 32];
  __shared__ u16 Bs[128 * 32];
  const int tid = threadIdx.x;
  const int lane = tid & 63, wave = tid >> 6;
  const int wr = wave >> 1, wc = wave & 1;
  const int row0 = blockIdx.y * 128, col0 = blockIdx.x * 128;

  f32x4 acc[4][4];
#pragma unroll
  for (int m = 0; m < 4; ++m)
#pragma unroll
    for (int n = 0; n < 4; ++n) acc[m][n] = (f32x4)(0.f);

  // staging constants: lane covers (row = seg*16 + lane/4, 16B granule sg = lane&3)
  const int srow = lane >> 2;
  const int sg = lane & 3;
  const int sf = (lane >> 3) & 3;            // = ((row>>1)&3) swizzle key
  const int kfetch = ((sg ^ sf) * 8);        // element offset of fetched granule

  const int r16 = lane & 15;
  const int g = lane >> 4;
  const int fr = (r16 >> 1) & 3;
  const int koff = ((g ^ fr) * 8);

  for (int k0 = 0; k0 < K; k0 += 32) {
    if (k0) __syncthreads();
#pragma unroll
    for (int p = 0; p < 2; ++p) {
      int seg = wave * 2 + p;
      int row = seg * 16 + srow;
      gl_lds16(A + (size_t)(row0 + row) * K + k0 + kfetch, &As[seg * 512 + lane * 8]);
      gl_lds16(BTm + (size_t)(col0 + row) * K + k0 + kfetch, &Bs[seg * 512 + lane * 8]);
    }
    __syncthreads();
    short8 af[4], bf[4];
#pragma unroll
    for (int m = 0; m < 4; ++m)
      af[m] = *(const short8*)&As[(wr * 64 + m * 16 + r16) * 32 + koff];
#pragma unroll
    for (int n = 0; n < 4; ++n)
      bf[n] = *(const short8*)&Bs[(wc * 64 + n * 16 + r16) * 32 + koff];
#pragma unroll
    for (int m = 0; m < 4; ++m)
#pragma unroll
      for (int n = 0; n < 4; ++n)
        acc[m][n] = MFMA(af[m], bf[n], acc[m][n]);
  }

  // epilogue: C[row][col], row = row0+wr*64+m*16+g*4+r, col = col0+wc*64+n*16+r16
#pragma unroll
  for (int m = 0; m < 4; ++m) {
    int rowg = row0 + wr * 64 + m * 16 + g * 4;
#pragma unroll
    for (int n = 0; n < 4; ++n) {
      int colg = col0 + wc * 64 + n * 16 + r16;
      float bv = bias[colg];
      if constexpr (EPI == 0) {
        int which = colg / Hc;
        int hc = colg - which * Hc;
        int h = hc >> 6, d = hc & 63;
#pragma unroll
        for (int r = 0; r < 4; ++r) {
          int mg = rowg + r;
          int b = mg >> 11, t = mg & 2047;
          float v = acc[m][n][r] + bv;
          size_t dst = ((size_t)(b * NH + h) * Tc + t) * HD + d;
          if (which == 0)      oQ[dst] = f2bf(v * QSCALE);
          else if (which == 1) oK[dst] = f2bf(v);
          else                 oV[dst] = f2bf(v);
        }
      } else {
#pragma unroll
        for (int r = 0; r < 4; ++r) {
          int mg = rowg + r;
          oF[(size_t)mg * Hc + colg] = acc[m][n][r] + bv;
        }
      }
    }
  }
}

// ---------------- flash attention: 64 q-rows/block (16/wave), KBLK=64 ----------------
__global__ __launch_bounds__(256) void k_attn(const u16* __restrict__ Qh,
                                              const u16* __restrict__ Kh,
                                              const u16* __restrict__ VT,
                                              const int* __restrict__ mask,
                                              u16* __restrict__ O) {
  __shared__ u16 Ks[64 * 64];
  __shared__ u16 Vs[64 * 64];
  __shared__ u16 Ps[4][16 * 64];
  const int tid = threadIdx.x, lane = tid & 63, wave = tid >> 6;
  const int bh = blockIdx.y;
  const int b = bh / NH;
  const int h = bh - b * NH;
  const int qt = blockIdx.x;
  const int q0 = qt * 64;
  const int r16 = lane & 15, g = lane >> 4;

  // Q fragments (rows q0 + wave*16 + r16), scale already folded in
  const u16* qbase = Qh + ((size_t)bh * Tc + q0 + wave * 16 + r16) * HD;
  short8 qf0 = *(const short8*)(qbase + g * 8);
  short8 qf1 = *(const short8*)(qbase + 32 + g * 8);

  f32x4 acc[4];
#pragma unroll
  for (int n = 0; n < 4; ++n) acc[n] = (f32x4)(0.f);
  float mrun[4], lrun[4];
#pragma unroll
  for (int r = 0; r < 4; ++r) { mrun[r] = -3.0e38f; lrun[r] = 0.f; }

  const int skey = lane >> 3;       // row within 8-row staging segment
  const int sgr = lane & 7;         // 16B granule slot
  const int sgd = ((sgr ^ skey) * 8);  // swizzled fetched granule (elems)

  const int ntiles = qt + 1;
  for (int it = 0; it < ntiles; ++it) {
    const int kb = it * 64;
    if (it) __syncthreads();
#pragma unroll
    for (int p = 0; p < 2; ++p) {
      int seg = wave * 2 + p;
      int rloc = seg * 8 + skey;  // key row (K) or d row (VT)
      gl_lds16(Kh + ((size_t)bh * Tc + kb + rloc) * HD + sgd, &Ks[seg * 512 + lane * 8]);
      gl_lds16(VT + ((size_t)bh * HD + rloc) * Tc + kb + sgd, &Vs[seg * 512 + lane * 8]);
    }
    __syncthreads();

    // S = Q K^T  (C layout: row q = g*4+r, col key = n*16+r16)
    f32x4 s[4];
#pragma unroll
    for (int n = 0; n < 4; ++n) {
      int key = n * 16 + r16;
      int k7 = key & 7;
      short8 kf0 = *(const short8*)&Ks[key * 64 + ((g ^ k7) * 8)];
      short8 kf1 = *(const short8*)&Ks[key * 64 + (((4 + g) ^ k7) * 8)];
      f32x4 z = (f32x4)(0.f);
      z = MFMA(qf0, kf0, z);
      z = MFMA(qf1, kf1, z);
      s[n] = z;
    }

    // key mask (+ causal on diagonal tile)
    const bool diag = (kb == q0);
#pragma unroll
    for (int n = 0; n < 4; ++n) {
      int keyg = kb + n * 16 + r16;
      int km = mask[b * Tc + keyg];
#pragma unroll
      for (int r = 0; r < 4; ++r) {
        bool ok = (km != 0);
        if (diag) ok = ok && (keyg <= q0 + wave * 16 + g * 4 + r);
        if (!ok) s[n][r] = -3.0e38f;
      }
    }

    // online softmax (base-2 domain)
    float alpha[4];
#pragma unroll
    for (int r = 0; r < 4; ++r) {
      float v = fmaxf(fmaxf(s[0][r], s[1][r]), fmaxf(s[2][r], s[3][r]));
      v = fmaxf(v, __shfl_xor(v, 1));
      v = fmaxf(v, __shfl_xor(v, 2));
      v = fmaxf(v, __shfl_xor(v, 4));
      v = fmaxf(v, __shfl_xor(v, 8));
      float nm = fmaxf(mrun[r], v);
      alpha[r] = fexp2(mrun[r] - nm);
      mrun[r] = nm;
    }
    float rs[4] = {0.f, 0.f, 0.f, 0.f};
#pragma unroll
    for (int n = 0; n < 4; ++n)
#pragma unroll
      for (int r = 0; r < 4; ++r) {
        float p = fexp2(s[n][r] - mrun[r]);
        s[n][r] = p;
        rs[r] += p;
      }
#pragma unroll
    for (int r = 0; r < 4; ++r) {
      float v = rs[r];
      v += __shfl_xor(v, 1);
      v += __shfl_xor(v, 2);
      v += __shfl_xor(v, 4);
      v += __shfl_xor(v, 8);
      lrun[r] = lrun[r] * alpha[r] + v;
      acc[0][r] *= alpha[r];
      acc[1][r] *= alpha[r];
      acc[2][r] *= alpha[r];
      acc[3][r] *= alpha[r];
    }

    // P (bf16) -> per-wave swizzled LDS, read back as A-frags
    u16* pw = &Ps[wave][0];
#pragma unroll
    for (int n = 0; n < 4; ++n) {
      int key = n * 16 + r16;
      int gk = key >> 3;
#pragma unroll
      for (int r = 0; r < 4; ++r) {
        int q = g * 4 + r;
        pw[q * 64 + ((gk ^ (q & 7)) * 8) + (key & 7)] = f2bf(s[n][r]);
      }
    }
    asm volatile("s_waitcnt lgkmcnt(0)" ::: "memory");
    short8 pa0, pa1;
    {
      int q7 = r16 & 7;
      pa0 = *(const short8*)&pw[r16 * 64 + ((g ^ q7) * 8)];
      pa1 = *(const short8*)&pw[r16 * 64 + (((4 + g) ^ q7) * 8)];
    }

    // O += P V  (B from VT tile: rows=d, inner=keys)
#pragma unroll
    for (int n = 0; n < 4; ++n) {
      int d = n * 16 + r16;
      int d7 = d & 7;
      short8 vf0 = *(const short8*)&Vs[d * 64 + ((g ^ d7) * 8)];
      short8 vf1 = *(const short8*)&Vs[d * 64 + (((4 + g) ^ d7) * 8)];
      acc[n] = MFMA(pa0, vf0, acc[n]);
      acc[n] = MFMA(pa1, vf1, acc[n]);
    }
  }

  // normalize + write O[b][t][h*64+d] (bf16)
#pragma unroll
  for (int r = 0; r < 4; ++r) {
    int qg = q0 + wave * 16 + g * 4 + r;
    float inv = 1.0f / lrun[r];
    u16* orow = O + ((size_t)(b * Tc + qg)) * Hc + h * 64;
#pragma unroll
    for (int n = 0; n < 4; ++n) orow[n * 16 + r16] = f2bf(acc[n][r] * inv);
  }
}

// ---------------- launch ----------------
extern "C" void kernel_launch(void* const* d_in, const int* in_sizes, int n_in,
                              void* d_out, int out_size, void* d_ws, size_t ws_size,
                              hipStream_t stream) {
  const float* x = (const float*)d_in[0];
  const int* mask = (const int*)d_in[1];
  const float* Wqkv = (const float*)d_in[2];
  const float* bqkv = (const float*)d_in[3];
  const float* Wproj = (const float*)d_in[4];
  const float* bproj = (const float*)d_in[5];
  float* out = (float*)d_out;

  char* ws = (char*)d_ws;
  size_t off = 0;
  auto alloc = [&](size_t bytes) {
    char* p = ws + off;
    off += (bytes + 255) & ~(size_t)255;
    return p;
  };
  u16* xb     = (u16*)alloc((size_t)BTc * Hc * 2);
  u16* WqkvT  = (u16*)alloc((size_t)N3 * Hc * 2);
  u16* WprojT = (u16*)alloc((size_t)Hc * Hc * 2);
  u16* Qh     = (u16*)alloc((size_t)BTc * Hc * 2);
  u16* Kh     = (u16*)alloc((size_t)BTc * Hc * 2);
  u16* Vh     = (u16*)alloc((size_t)BTc * Hc * 2);
  u16* VT     = (u16*)alloc((size_t)BTc * Hc * 2);
  u16* Ob     = xb;  // alias: xb dead after GEMM1, reused for attention output

  int n8 = BTc * Hc / 8;
  k_cvt<<<(n8 + 255) / 256, 256, 0, stream>>>((const float4*)x, (uint4*)xb, n8);
  k_transpose_w<<<dim3(N3 / 64, Hc / 64), dim3(64, 4), 0, stream>>>(Wqkv, WqkvT, Hc, N3);
  k_transpose_w<<<dim3(Hc / 64, Hc / 64), dim3(64, 4), 0, stream>>>(Wproj, WprojT, Hc, Hc);
  k_gemm<0><<<dim3(N3 / 128, BTc / 128), 256, 0, stream>>>(xb, WqkvT, bqkv, Qh, Kh, Vh,
                                                           nullptr, BTc, N3, Hc);
  k_transpose_v<<<dim3(Tc / 64, Bc * NH), dim3(64, 4), 0, stream>>>(Vh, VT);
  k_attn<<<dim3(Tc / 64, Bc * NH), 256, 0, stream>>>(Qh, Kh, VT, mask, Ob);
  k_gemm<1><<<dim3(Hc / 128, BTc / 128), 256, 0, stream>>>(Ob, WprojT, bproj, nullptr,
                                                           nullptr, nullptr, out, BTc, Hc, Hc);
}